// Round 8
// baseline (159.655 us; speedup 1.0000x reference)
//
#include <hip/hip_runtime.h>
#include <hip/hip_bf16.h>
#include <stdint.h>

typedef __bf16 bf16x8 __attribute__((ext_vector_type(8)));
typedef float f32x4 __attribute__((ext_vector_type(4)));

__device__ __forceinline__ uint16_t f32_to_bf16_rne(float f) {
    uint32_t u = __float_as_uint(f);
    u += 0x7fffu + ((u >> 16) & 1u);
    return (uint16_t)(u >> 16);
}

// Convert x and w to bf16 (RNE) AND zero d_out (third segment), one kernel.
__global__ void cvt2z_kernel(const float* __restrict__ a, long na4,
                             const float* __restrict__ b, long nb4,
                             uint16_t* __restrict__ oa, uint16_t* __restrict__ ob,
                             float4* __restrict__ z, long nz4) {
    long i = (long)blockIdx.x * blockDim.x + threadIdx.x;
    const long stride = (long)gridDim.x * blockDim.x;
    const long nab = na4 + nb4;
    const long tot = nab + nz4;
    for (; i < tot; i += stride) {
        if (i < nab) {
            const float4* src; ushort4* dst; long j;
            if (i < na4) { src = (const float4*)a; dst = (ushort4*)oa; j = i; }
            else         { src = (const float4*)b; dst = (ushort4*)ob; j = i - na4; }
            float4 f = src[j];
            ushort4 o;
            o.x = f32_to_bf16_rne(f.x);
            o.y = f32_to_bf16_rne(f.y);
            o.z = f32_to_bf16_rne(f.z);
            o.w = f32_to_bf16_rne(f.w);
            dst[j] = o;
        } else {
            z[i - nab] = (float4){0.f, 0.f, 0.f, 0.f};
        }
    }
}

// ---------------------------------------------------------------------------
// m201-template GEMM with split-K x2 and atomic accumulation.
// BM=BN=256, BK=64, 512 threads (8 waves = 2M x 4N), per-wave 128x64 output
// (acc 8x4 f32x4 = 128 VGPR).  LDS 128 KiB = 2 K-tile buffers x (A 256x64 +
// B 256x64) bf16.  Rows are 128 B; 16-B chunk c of row r stored at slot
// c ^ (r&7)  (2-way-free bank pattern, same class as the r6/r7 measured-0
// layout).
// 8 phases per 2 K-tiles; per phase: {ds_reads; stage half-tile; [vmcnt];
// barrier; lgkmcnt(0); setprio(1); 16 MFMA (one quadrant x K64);
// setprio(0); barrier}.  Quadrant order per K-tile: A0B0, A1B0, A1B1, A0B1
// (reads 12/8/4/0).  vmcnt(6) only at phases 4 and 8: 3 half-tiles always
// in flight.  Half-tile staging order: B1(t+1)@ph1, A0+A1(t+2)@ph3,
// B0(t+2)@ph4 — every staged region's last read is >=1 barrier earlier.
// Grid = 2 x (M/256) x (N/256): slice s computes K-half s, atomicAdd into
// zeroed C (slice 0 adds bias).  Exactly two commutative fp32 adds onto
// exact 0.0 -> bitwise deterministic.
// ---------------------------------------------------------------------------

#define GLD(gp, lp) __builtin_amdgcn_global_load_lds(                           \
    (const __attribute__((address_space(1))) uint32_t*)(gp),                    \
    (__attribute__((address_space(3))) uint32_t*)(void*)(lp), 16, 0, 0)

#define LD8(p) (*(const bf16x8*)(p))
#define MM(a, b, c) __builtin_amdgcn_mfma_f32_16x16x32_bf16(a, b, c, 0, 0, 0)

// Stage A half-tile H of a K-tile (2 gloads); KB = ktile*128 byte offset.
#define STA(H, KB, BW) do {                                                     \
    GLD(pA##H##0 + (KB), lds + (BW) + (H) * 16384 + t16);                       \
    GLD(pA##H##1 + (KB), lds + (BW) + (H) * 16384 + 8192 + t16);                \
} while (0)
#define STB(H, KB, BW) do {                                                     \
    GLD(pB##H##0 + (KB), lds + (BW) + 32768 + (H) * 16384 + t16);               \
    GLD(pB##H##1 + (KB), lds + (BW) + 32768 + (H) * 16384 + 8192 + t16);        \
} while (0)

// Read one A quadrant (4 m-frags x 2 k-slabs) / one B quarter (2 n-frags x 2).
#define RDA(D, AB, BUF) do {                                                    \
    const uint8_t* p_ = lds + (BUF) + (AB);                                     \
    D##00 = LD8(p_ + 0 * 2048 + sb0); D##01 = LD8(p_ + 0 * 2048 + sb1);         \
    D##10 = LD8(p_ + 1 * 2048 + sb0); D##11 = LD8(p_ + 1 * 2048 + sb1);         \
    D##20 = LD8(p_ + 2 * 2048 + sb0); D##21 = LD8(p_ + 2 * 2048 + sb1);         \
    D##30 = LD8(p_ + 3 * 2048 + sb0); D##31 = LD8(p_ + 3 * 2048 + sb1);         \
} while (0)
#define RDB(D, BB, BUF) do {                                                    \
    const uint8_t* p_ = lds + (BUF) + (BB);                                     \
    D##00 = LD8(p_ + 0 * 2048 + sb0); D##01 = LD8(p_ + 0 * 2048 + sb1);         \
    D##10 = LD8(p_ + 1 * 2048 + sb0); D##11 = LD8(p_ + 1 * 2048 + sb1);         \
} while (0)

// One quadrant x K64: 16 MFMA.  P = A set (4 m-frags), Q = B set (2 n-frags).
#define MFQ(P, Q, MB, NB) do {                                                  \
    acc[(MB)+0][(NB)+0] = MM(P##00, Q##00, acc[(MB)+0][(NB)+0]);                \
    acc[(MB)+1][(NB)+0] = MM(P##10, Q##00, acc[(MB)+1][(NB)+0]);                \
    acc[(MB)+2][(NB)+0] = MM(P##20, Q##00, acc[(MB)+2][(NB)+0]);                \
    acc[(MB)+3][(NB)+0] = MM(P##30, Q##00, acc[(MB)+3][(NB)+0]);                \
    acc[(MB)+0][(NB)+1] = MM(P##00, Q##10, acc[(MB)+0][(NB)+1]);                \
    acc[(MB)+1][(NB)+1] = MM(P##10, Q##10, acc[(MB)+1][(NB)+1]);                \
    acc[(MB)+2][(NB)+1] = MM(P##20, Q##10, acc[(MB)+2][(NB)+1]);                \
    acc[(MB)+3][(NB)+1] = MM(P##30, Q##10, acc[(MB)+3][(NB)+1]);                \
    acc[(MB)+0][(NB)+0] = MM(P##01, Q##01, acc[(MB)+0][(NB)+0]);                \
    acc[(MB)+1][(NB)+0] = MM(P##11, Q##01, acc[(MB)+1][(NB)+0]);                \
    acc[(MB)+2][(NB)+0] = MM(P##21, Q##01, acc[(MB)+2][(NB)+0]);                \
    acc[(MB)+3][(NB)+0] = MM(P##31, Q##01, acc[(MB)+3][(NB)+0]);                \
    acc[(MB)+0][(NB)+1] = MM(P##01, Q##11, acc[(MB)+0][(NB)+1]);                \
    acc[(MB)+1][(NB)+1] = MM(P##11, Q##11, acc[(MB)+1][(NB)+1]);                \
    acc[(MB)+2][(NB)+1] = MM(P##21, Q##11, acc[(MB)+2][(NB)+1]);                \
    acc[(MB)+3][(NB)+1] = MM(P##31, Q##11, acc[(MB)+3][(NB)+1]);                \
} while (0)

#define PH_MID() do {                                                           \
    __builtin_amdgcn_s_barrier();                                               \
    asm volatile("s_waitcnt lgkmcnt(0)" ::: "memory");                          \
    __builtin_amdgcn_sched_barrier(0);                                          \
    __builtin_amdgcn_s_setprio(1);                                              \
} while (0)
#define PH_END() do {                                                           \
    __builtin_amdgcn_s_setprio(0);                                              \
    __builtin_amdgcn_s_barrier();                                               \
    __builtin_amdgcn_sched_barrier(0);                                          \
} while (0)
#define VMC6 asm volatile("s_waitcnt vmcnt(6)" ::: "memory")
#define VMC0 asm volatile("s_waitcnt vmcnt(0)" ::: "memory")

__global__ __launch_bounds__(512, 2) void gemm_sk_bf16(
    const uint16_t* __restrict__ A,   // M x K bf16 (x)
    const uint16_t* __restrict__ B,   // N x K bf16 (weight)
    const float* __restrict__ bias,
    float* __restrict__ C,            // zeroed; atomic accumulate
    int M, int N, int K)
{
    extern __shared__ __align__(16) uint8_t lds[];
    const int tid  = threadIdx.x;
    const int lane = tid & 63;
    const int wave = tid >> 6;
    const int wm = wave >> 2;   // 0..1 (M halves of the 256 tile)
    const int wc = wave & 3;    // 0..3 (N quarters)

    // Bijective XCD-aware swizzle over the full grid.
    const int nwg = gridDim.x;
    int swz;
    {
        const int q = nwg >> 3, r = nwg & 7;
        const int xcd = blockIdx.x & 7, k = blockIdx.x >> 3;
        swz = (xcd < r ? xcd * (q + 1) : r * (q + 1) + (xcd - r) * q) + k;
    }
    const int MB = M >> 8;
    const int ntile = MB * (N >> 8);
    const int slice = swz / ntile;          // 0 or 1 (K half)
    const int tilei = swz % ntile;
    const int brow = tilei % MB;
    const int bcol = tilei / MB;
    const int Ksl = K >> 1;                  // per-slice K

    // ---- staging pointers (pre-swizzled global source, linear LDS dest) ----
    const int t16  = tid * 16;
    const int trow = tid >> 3;               // 0..63
    const uint32_t cc16 = (uint32_t)(((tid & 7) ^ (trow & 7)) << 4);
    const size_t K2 = (size_t)K * 2;
    const uint8_t* Ab = (const uint8_t*)A + (size_t)slice * Ksl * 2;
    const uint8_t* Bb = (const uint8_t*)B + (size_t)slice * Ksl * 2;
    const uint8_t* pA00 = Ab + (size_t)(brow * 256 +   0 + trow) * K2 + cc16;
    const uint8_t* pA01 = Ab + (size_t)(brow * 256 +  64 + trow) * K2 + cc16;
    const uint8_t* pA10 = Ab + (size_t)(brow * 256 + 128 + trow) * K2 + cc16;
    const uint8_t* pA11 = Ab + (size_t)(brow * 256 + 192 + trow) * K2 + cc16;
    const uint8_t* pB00 = Bb + (size_t)(bcol * 256 +   0 + trow) * K2 + cc16;
    const uint8_t* pB01 = Bb + (size_t)(bcol * 256 +  64 + trow) * K2 + cc16;
    const uint8_t* pB10 = Bb + (size_t)(bcol * 256 + 128 + trow) * K2 + cc16;
    const uint8_t* pB11 = Bb + (size_t)(bcol * 256 + 192 + trow) * K2 + cc16;

    // ---- fragment read offsets (swizzled; row&7 == lm&7 for all frags) ----
    const int lm = lane & 15, g = lane >> 4;
    const int sb0 = ((g ^ (lm & 7)) << 4);
    const int sb1 = (((g + 4) ^ (lm & 7)) << 4);
    const uint32_t aQ0 = (uint32_t)((wm * 128 +  0 + lm) * 128);
    const uint32_t aQ1 = (uint32_t)((wm * 128 + 64 + lm) * 128);
    const uint32_t bH0 = (uint32_t)(32768 + (wc * 64 +  0 + lm) * 128);
    const uint32_t bH1 = (uint32_t)(32768 + (wc * 64 + 32 + lm) * 128);

    f32x4 acc[8][4];
#pragma unroll
    for (int m = 0; m < 8; ++m)
#pragma unroll
        for (int n = 0; n < 4; ++n)
            acc[m][n] = (f32x4){0.f, 0.f, 0.f, 0.f};

    // Fragment register sets: FA=A0, GA=A1 (4x2 each), FB=B0, GB=B1 (2x2).
    bf16x8 FA00, FA01, FA10, FA11, FA20, FA21, FA30, FA31;
    bf16x8 GA00, GA01, GA10, GA11, GA20, GA21, GA30, GA31;
    bf16x8 FB00, FB01, FB10, FB11;
    bf16x8 GB00, GB01, GB10, GB11;

    const int ntp = Ksl >> 7;    // K-tile pairs; launcher guarantees >= 2

    // Prologue: tile0 all 4 halves -> buf0; tile1 A0,A1,B0 -> buf1.
    STA(0, 0, 0); STA(1, 0, 0); STB(0, 0, 0); STB(1, 0, 0);
    STA(0, 128, 65536); STA(1, 128, 65536); STB(0, 128, 65536);
    VMC6;                                    // tile0 landed; 3 halves in flight
    __builtin_amdgcn_s_barrier();
    __builtin_amdgcn_sched_barrier(0);

    for (int i = 0; i < ntp - 1; ++i) {
        const int kb = i * 256;
        // ---- Group A: K-tile 2i from buf0 ----
        RDA(FA, aQ0, 0); RDB(FB, bH0, 0);
        STB(1, kb + 128, 65536);             // complete tile t+1
        PH_MID(); MFQ(FA, FB, 0, 0); PH_END();

        RDA(GA, aQ1, 0);
        PH_MID(); MFQ(GA, FB, 4, 0); PH_END();

        RDB(GB, bH1, 0);
        STA(0, kb + 256, 0); STA(1, kb + 256, 0);   // tile t+2 into buf0
        PH_MID(); MFQ(GA, GB, 4, 2); PH_END();

        STB(0, kb + 256, 0);
        VMC6;                                // publishes tile t+1
        PH_MID(); MFQ(FA, GB, 0, 2); PH_END();

        // ---- Group B: K-tile 2i+1 from buf1 ----
        RDA(FA, aQ0, 65536); RDB(FB, bH0, 65536);
        STB(1, kb + 256, 0);                 // complete tile t+2
        PH_MID(); MFQ(FA, FB, 0, 0); PH_END();

        RDA(GA, aQ1, 65536);
        PH_MID(); MFQ(GA, FB, 4, 0); PH_END();

        RDB(GB, bH1, 65536);
        STA(0, kb + 384, 65536); STA(1, kb + 384, 65536);  // tile t+3
        PH_MID(); MFQ(GA, GB, 4, 2); PH_END();

        STB(0, kb + 384, 65536);
        VMC6;                                // publishes tile t+2
        PH_MID(); MFQ(FA, GB, 0, 2); PH_END();
    }
    {   // Tail pair: tiles 2ntp-2 (buf0) and 2ntp-1 (buf1).
        const int kb = (ntp - 1) * 256;
        RDA(FA, aQ0, 0); RDB(FB, bH0, 0);
        STB(1, kb + 128, 65536);             // complete the last tile
        PH_MID(); MFQ(FA, FB, 0, 0); PH_END();
        RDA(GA, aQ1, 0);
        PH_MID(); MFQ(GA, FB, 4, 0); PH_END();
        RDB(GB, bH1, 0);
        PH_MID(); MFQ(GA, GB, 4, 2); PH_END();
        VMC0;                                // drain: last tile fully landed
        PH_MID(); MFQ(FA, GB, 0, 2); PH_END();

        RDA(FA, aQ0, 65536); RDB(FB, bH0, 65536);
        PH_MID(); MFQ(FA, FB, 0, 0); PH_END();
        RDA(GA, aQ1, 65536);
        PH_MID(); MFQ(GA, FB, 4, 0); PH_END();
        RDB(GB, bH1, 65536);
        PH_MID(); MFQ(GA, GB, 4, 2); PH_END();
        PH_MID(); MFQ(FA, GB, 0, 2); PH_END();
    }

    // Epilogue: atomic accumulate.  D mapping: col = lane&15, row = (lane>>4)*4+t.
    const int crow0 = brow * 256 + wm * 128 + (lane >> 4) * 4;
    const int ccol0 = bcol * 256 + wc * 64 + lm;
#pragma unroll
    for (int nf = 0; nf < 4; ++nf) {
        const int col = ccol0 + nf * 16;
        const float bv = (slice == 0) ? bias[col] : 0.f;
#pragma unroll
        for (int mf = 0; mf < 8; ++mf) {
#pragma unroll
            for (int tt = 0; tt < 4; ++tt) {
                const int row = crow0 + mf * 16 + tt;
                atomicAdd(&C[(size_t)row * N + col], acc[mf][nf][tt] + bv);
            }
        }
    }
}

// ---------------------------------------------------------------------------
// Fallback 1: verified m97-structure 128x128 kernel (needs plain cvt + store).
// ---------------------------------------------------------------------------
__global__ void cvt2_kernel(const float* __restrict__ a, long na4,
                            const float* __restrict__ b, long nb4,
                            uint16_t* __restrict__ oa, uint16_t* __restrict__ ob) {
    long i = (long)blockIdx.x * blockDim.x + threadIdx.x;
    const long stride = (long)gridDim.x * blockDim.x;
    const long tot = na4 + nb4;
    for (; i < tot; i += stride) {
        const float4* src; ushort4* dst; long j;
        if (i < na4) { src = (const float4*)a; dst = (ushort4*)oa; j = i; }
        else         { src = (const float4*)b; dst = (ushort4*)ob; j = i - na4; }
        float4 f = src[j];
        ushort4 o;
        o.x = f32_to_bf16_rne(f.x);
        o.y = f32_to_bf16_rne(f.y);
        o.z = f32_to_bf16_rne(f.z);
        o.w = f32_to_bf16_rne(f.w);
        dst[j] = o;
    }
}

__global__ __launch_bounds__(256) void gemm_bf16_kernel(
    const uint16_t* __restrict__ A,
    const uint16_t* __restrict__ B,
    const float* __restrict__ bias,
    float* __restrict__ C, int M, int N, int K)
{
    __shared__ __align__(16) uint16_t Alds[128 * 32];
    __shared__ __align__(16) uint16_t Blds[128 * 32];

    const int tid  = threadIdx.x;
    const int lane = tid & 63;
    const int wave = tid >> 6;
    const int wm = wave >> 1, wn = wave & 1;

    const int MBl = M >> 7;
    const int brow = blockIdx.x % MBl;
    const int bcol = blockIdx.x / MBl;

    const int off0 = wave * 1024 + lane * 16;
    const int row0 = off0 >> 6;
    const int colb = off0 & 63;

    const uint8_t* gA0 = (const uint8_t*)A + ((size_t)(brow * 128 + row0) * K) * 2 + colb;
    const uint8_t* gA1 = gA0 + (size_t)64 * K * 2;
    const uint8_t* gB0 = (const uint8_t*)B + ((size_t)(bcol * 128 + row0) * K) * 2 + colb;
    const uint8_t* gB1 = gB0 + (size_t)64 * K * 2;

    uint32_t* lA0 = (uint32_t*)((uint8_t*)Alds + off0);
    uint32_t* lA1 = (uint32_t*)((uint8_t*)Alds + off0 + 4096);
    uint32_t* lB0 = (uint32_t*)((uint8_t*)Blds + off0);
    uint32_t* lB1 = (uint32_t*)((uint8_t*)Blds + off0 + 4096);

#define STAGE_OLD() do {                                                                   \
    __builtin_amdgcn_global_load_lds((const __attribute__((address_space(1))) uint32_t*)gA0, \
                                     (__attribute__((address_space(3))) uint32_t*)lA0, 16, 0, 0); \
    __builtin_amdgcn_global_load_lds((const __attribute__((address_space(1))) uint32_t*)gA1, \
                                     (__attribute__((address_space(3))) uint32_t*)lA1, 16, 0, 0); \
    __builtin_amdgcn_global_load_lds((const __attribute__((address_space(1))) uint32_t*)gB0, \
                                     (__attribute__((address_space(3))) uint32_t*)lB0, 16, 0, 0); \
    __builtin_amdgcn_global_load_lds((const __attribute__((address_space(1))) uint32_t*)gB1, \
                                     (__attribute__((address_space(3))) uint32_t*)lB1, 16, 0, 0); \
    gA0 += 64; gA1 += 64; gB0 += 64; gB1 += 64;                                            \
} while (0)

    f32x4 acc[4][4];
#pragma unroll
    for (int mf = 0; mf < 4; ++mf)
#pragma unroll
        for (int nf = 0; nf < 4; ++nf)
            acc[mf][nf] = (f32x4){0.f, 0.f, 0.f, 0.f};

    const int nk = K >> 5;
    STAGE_OLD();

    const int arow = wm * 64 + (lane & 15);
    const int brw  = wn * 64 + (lane & 15);
    const int ke   = (lane >> 4) * 8;

    for (int kt = 0; kt < nk; ++kt) {
        __syncthreads();
        bf16x8 af[4], bfr[4];
#pragma unroll
        for (int mf = 0; mf < 4; ++mf)
            af[mf] = *(const bf16x8*)(&Alds[(arow + mf * 16) * 32 + ke]);
#pragma unroll
        for (int nf = 0; nf < 4; ++nf)
            bfr[nf] = *(const bf16x8*)(&Blds[(brw + nf * 16) * 32 + ke]);
        __syncthreads();
        if (kt + 1 < nk) STAGE_OLD();
#pragma unroll
        for (int mf = 0; mf < 4; ++mf)
#pragma unroll
            for (int nf = 0; nf < 4; ++nf)
                acc[mf][nf] = __builtin_amdgcn_mfma_f32_16x16x32_bf16(
                    af[mf], bfr[nf], acc[mf][nf], 0, 0, 0);
    }
#undef STAGE_OLD

    const int crow0 = brow * 128 + wm * 64 + (lane >> 4) * 4;
    const int ccol0 = bcol * 128 + wn * 64 + (lane & 15);
#pragma unroll
    for (int nf = 0; nf < 4; ++nf) {
        const int col = ccol0 + nf * 16;
        const float bv = bias[col];
#pragma unroll
        for (int mf = 0; mf < 4; ++mf) {
#pragma unroll
            for (int t = 0; t < 4; ++t) {
                const int row = crow0 + mf * 16 + t;
                C[(size_t)row * N + col] = acc[mf][nf][t] + bv;
            }
        }
    }
}

// Fallback 2: fp32 vector GEMM, one block per row.
__global__ void gemm_fallback(const float* __restrict__ x, const float* __restrict__ w,
                              const float* __restrict__ bias, float* __restrict__ out,
                              int M, int N, int K) {
    extern __shared__ float xs[];
    const int b = blockIdx.x;
    for (int k = threadIdx.x; k < K; k += blockDim.x) xs[k] = x[(size_t)b * K + k];
    __syncthreads();
    for (int j = threadIdx.x; j < N; j += blockDim.x) {
        const float* wr = w + (size_t)j * K;
        float s = 0.f;
        for (int k = 0; k < K; ++k) s += xs[k] * wr[k];
        out[(size_t)b * N + j] = s + bias[j];
    }
}

extern "C" void kernel_launch(void* const* d_in, const int* in_sizes, int n_in,
                              void* d_out, int out_size, void* d_ws, size_t ws_size,
                              hipStream_t stream) {
    const float* x    = (const float*)d_in[0];
    const float* w    = (const float*)d_in[1];
    const float* bias = (const float*)d_in[2];
    float* out = (float*)d_out;

    const int N = in_sizes[2];
    const int K = in_sizes[1] / N;
    const int M = in_sizes[0] / K;

    const size_t need = ((size_t)M * K + (size_t)N * K) * 2;
    const bool ws_ok = ws_size >= need;

    if ((M % 256 == 0) && (N % 256 == 0) && (K % 256 == 0) && (K >= 512) && ws_ok) {
        uint16_t* xb = (uint16_t*)d_ws;
        uint16_t* wb = xb + (size_t)M * K;
        const long na4 = (long)M * K / 4, nb4 = (long)N * K / 4;
        const long nz4 = (long)out_size / 4;
        cvt2z_kernel<<<2048, 256, 0, stream>>>(x, na4, w, nb4, xb, wb,
                                               (float4*)out, nz4);
        (void)hipFuncSetAttribute((const void*)gemm_sk_bf16,
                                  hipFuncAttributeMaxDynamicSharedMemorySize, 131072);
        dim3 grid(2 * (M / 256) * (N / 256));
        gemm_sk_bf16<<<grid, 512, 131072, stream>>>(xb, wb, bias, out, M, N, K);
    } else if ((M % 128 == 0) && (N % 128 == 0) && (K % 32 == 0) && ws_ok) {
        uint16_t* xb = (uint16_t*)d_ws;
        uint16_t* wb = xb + (size_t)M * K;
        const long na4 = (long)M * K / 4, nb4 = (long)N * K / 4;
        cvt2_kernel<<<2048, 256, 0, stream>>>(x, na4, w, nb4, xb, wb);
        dim3 grid((M / 128) * (N / 128));
        gemm_bf16_kernel<<<grid, 256, 0, stream>>>(xb, wb, bias, out, M, N, K);
    } else {
        gemm_fallback<<<M, 256, (size_t)K * 4, stream>>>(x, w, bias, out, M, N, K);
    }
}

// Round 9
// 134.167 us; speedup vs baseline: 1.1900x; 1.1900x over previous
//
#include <hip/hip_runtime.h>
#include <hip/hip_bf16.h>
#include <stdint.h>

typedef __bf16 bf16x8 __attribute__((ext_vector_type(8)));
typedef float f32x4 __attribute__((ext_vector_type(4)));

__device__ __forceinline__ uint16_t f32_to_bf16_rne(float f) {
    uint32_t u = __float_as_uint(f);
    u += 0x7fffu + ((u >> 16) & 1u);
    return (uint16_t)(u >> 16);
}

// Convert two fp32 arrays to bf16 (RNE) in one grid-stride kernel.
__global__ void cvt2_kernel(const float* __restrict__ a, long na4,
                            const float* __restrict__ b, long nb4,
                            uint16_t* __restrict__ oa, uint16_t* __restrict__ ob) {
    long i = (long)blockIdx.x * blockDim.x + threadIdx.x;
    const long stride = (long)gridDim.x * blockDim.x;
    const long tot = na4 + nb4;
    for (; i < tot; i += stride) {
        const float4* src; ushort4* dst; long j;
        if (i < na4) { src = (const float4*)a; dst = (ushort4*)oa; j = i; }
        else         { src = (const float4*)b; dst = (ushort4*)ob; j = i - na4; }
        float4 f = src[j];
        ushort4 o;
        o.x = f32_to_bf16_rne(f.x);
        o.y = f32_to_bf16_rne(f.y);
        o.z = f32_to_bf16_rne(f.z);
        o.w = f32_to_bf16_rne(f.w);
        dst[j] = o;
    }
}

// out = p0 + p1 (bias already folded into p0 by GEMM slice 0).
__global__ void reduce2_kernel(const float4* __restrict__ p0,
                               const float4* __restrict__ p1,
                               float4* __restrict__ out, long n4) {
    long i = (long)blockIdx.x * blockDim.x + threadIdx.x;
    const long stride = (long)gridDim.x * blockDim.x;
    for (; i < n4; i += stride) {
        float4 a = p0[i], b = p1[i], r;
        r.x = a.x + b.x; r.y = a.y + b.y; r.z = a.z + b.z; r.w = a.w + b.w;
        out[i] = r;
    }
}

// ---------------------------------------------------------------------------
// m201-template GEMM with split-K x2, partial-buffer epilogue (no atomics).
// BM=BN=256, BK=64, 512 threads (8 waves = 2M x 4N), per-wave 128x64 output.
// LDS 128 KiB = 2 K-tile buffers x (A 256x64 + B 256x64) bf16; rows 128 B,
// 16-B chunk c of row r at slot c ^ (r&7) (measured-0-conflict class).
// 8 phases / 2 K-tiles; per phase {ds_reads; stage half-tile; [vmcnt];
// barrier; lgkmcnt(0); setprio(1); 16 MFMA quadrant; setprio(0); barrier}.
// vmcnt(6) only at phases 4 and 8 (3 half-tiles always in flight).
// Grid = 2 x (M/256) x (N/256); slice s stores its tile to P + s*M*N
// (slice 0 adds bias).  Separate reduce kernel sums the two partials.
// ---------------------------------------------------------------------------

#define GLD(gp, lp) __builtin_amdgcn_global_load_lds(                           \
    (const __attribute__((address_space(1))) uint32_t*)(gp),                    \
    (__attribute__((address_space(3))) uint32_t*)(void*)(lp), 16, 0, 0)

#define LD8(p) (*(const bf16x8*)(p))
#define MM(a, b, c) __builtin_amdgcn_mfma_f32_16x16x32_bf16(a, b, c, 0, 0, 0)

#define STA(H, KB, BW) do {                                                     \
    GLD(pA##H##0 + (KB), lds + (BW) + (H) * 16384 + t16);                       \
    GLD(pA##H##1 + (KB), lds + (BW) + (H) * 16384 + 8192 + t16);                \
} while (0)
#define STB(H, KB, BW) do {                                                     \
    GLD(pB##H##0 + (KB), lds + (BW) + 32768 + (H) * 16384 + t16);               \
    GLD(pB##H##1 + (KB), lds + (BW) + 32768 + (H) * 16384 + 8192 + t16);        \
} while (0)

#define RDA(D, AB, BUF) do {                                                    \
    const uint8_t* p_ = lds + (BUF) + (AB);                                     \
    D##00 = LD8(p_ + 0 * 2048 + sb0); D##01 = LD8(p_ + 0 * 2048 + sb1);         \
    D##10 = LD8(p_ + 1 * 2048 + sb0); D##11 = LD8(p_ + 1 * 2048 + sb1);         \
    D##20 = LD8(p_ + 2 * 2048 + sb0); D##21 = LD8(p_ + 2 * 2048 + sb1);         \
    D##30 = LD8(p_ + 3 * 2048 + sb0); D##31 = LD8(p_ + 3 * 2048 + sb1);         \
} while (0)
#define RDB(D, BB, BUF) do {                                                    \
    const uint8_t* p_ = lds + (BUF) + (BB);                                     \
    D##00 = LD8(p_ + 0 * 2048 + sb0); D##01 = LD8(p_ + 0 * 2048 + sb1);         \
    D##10 = LD8(p_ + 1 * 2048 + sb0); D##11 = LD8(p_ + 1 * 2048 + sb1);         \
} while (0)

#define MFQ(P, Q, MB, NB) do {                                                  \
    acc[(MB)+0][(NB)+0] = MM(P##00, Q##00, acc[(MB)+0][(NB)+0]);                \
    acc[(MB)+1][(NB)+0] = MM(P##10, Q##00, acc[(MB)+1][(NB)+0]);                \
    acc[(MB)+2][(NB)+0] = MM(P##20, Q##00, acc[(MB)+2][(NB)+0]);                \
    acc[(MB)+3][(NB)+0] = MM(P##30, Q##00, acc[(MB)+3][(NB)+0]);                \
    acc[(MB)+0][(NB)+1] = MM(P##00, Q##10, acc[(MB)+0][(NB)+1]);                \
    acc[(MB)+1][(NB)+1] = MM(P##10, Q##10, acc[(MB)+1][(NB)+1]);                \
    acc[(MB)+2][(NB)+1] = MM(P##20, Q##10, acc[(MB)+2][(NB)+1]);                \
    acc[(MB)+3][(NB)+1] = MM(P##30, Q##10, acc[(MB)+3][(NB)+1]);                \
    acc[(MB)+0][(NB)+0] = MM(P##01, Q##01, acc[(MB)+0][(NB)+0]);                \
    acc[(MB)+1][(NB)+0] = MM(P##11, Q##01, acc[(MB)+1][(NB)+0]);                \
    acc[(MB)+2][(NB)+0] = MM(P##21, Q##01, acc[(MB)+2][(NB)+0]);                \
    acc[(MB)+3][(NB)+0] = MM(P##31, Q##01, acc[(MB)+3][(NB)+0]);                \
    acc[(MB)+0][(NB)+1] = MM(P##01, Q##11, acc[(MB)+0][(NB)+1]);                \
    acc[(MB)+1][(NB)+1] = MM(P##11, Q##11, acc[(MB)+1][(NB)+1]);                \
    acc[(MB)+2][(NB)+1] = MM(P##21, Q##11, acc[(MB)+2][(NB)+1]);                \
    acc[(MB)+3][(NB)+1] = MM(P##31, Q##11, acc[(MB)+3][(NB)+1]);                \
} while (0)

#define PH_MID() do {                                                           \
    __builtin_amdgcn_s_barrier();                                               \
    asm volatile("s_waitcnt lgkmcnt(0)" ::: "memory");                          \
    __builtin_amdgcn_sched_barrier(0);                                          \
    __builtin_amdgcn_s_setprio(1);                                              \
} while (0)
#define PH_END() do {                                                           \
    __builtin_amdgcn_s_setprio(0);                                              \
    __builtin_amdgcn_s_barrier();                                               \
    __builtin_amdgcn_sched_barrier(0);                                          \
} while (0)
#define VMC6 asm volatile("s_waitcnt vmcnt(6)" ::: "memory")
#define VMC0 asm volatile("s_waitcnt vmcnt(0)" ::: "memory")

__global__ __launch_bounds__(512, 2) void gemm_sk_bf16(
    const uint16_t* __restrict__ A,   // M x K bf16 (x)
    const uint16_t* __restrict__ B,   // N x K bf16 (weight)
    const float* __restrict__ bias,
    float* __restrict__ P,            // partials: slice s at P + s*M*N
    int M, int N, int K)
{
    extern __shared__ __align__(16) uint8_t lds[];
    const int tid  = threadIdx.x;
    const int lane = tid & 63;
    const int wave = tid >> 6;
    const int wm = wave >> 2;   // 0..1 (M halves of the 256 tile)
    const int wc = wave & 3;    // 0..3 (N quarters)

    // Bijective XCD-aware swizzle over the full grid.
    const int nwg = gridDim.x;
    int swz;
    {
        const int q = nwg >> 3, r = nwg & 7;
        const int xcd = blockIdx.x & 7, k = blockIdx.x >> 3;
        swz = (xcd < r ? xcd * (q + 1) : r * (q + 1) + (xcd - r) * q) + k;
    }
    const int MB = M >> 8;
    const int ntile = MB * (N >> 8);
    const int slice = swz / ntile;          // 0 or 1 (K half)
    const int tilei = swz % ntile;
    const int brow = tilei % MB;
    const int bcol = tilei / MB;
    const int Ksl = K >> 1;                  // per-slice K

    // ---- staging pointers (pre-swizzled global source, linear LDS dest) ----
    const int t16  = tid * 16;
    const int trow = tid >> 3;               // 0..63
    const uint32_t cc16 = (uint32_t)(((tid & 7) ^ (trow & 7)) << 4);
    const size_t K2 = (size_t)K * 2;
    const uint8_t* Ab = (const uint8_t*)A + (size_t)slice * Ksl * 2;
    const uint8_t* Bb = (const uint8_t*)B + (size_t)slice * Ksl * 2;
    const uint8_t* pA00 = Ab + (size_t)(brow * 256 +   0 + trow) * K2 + cc16;
    const uint8_t* pA01 = Ab + (size_t)(brow * 256 +  64 + trow) * K2 + cc16;
    const uint8_t* pA10 = Ab + (size_t)(brow * 256 + 128 + trow) * K2 + cc16;
    const uint8_t* pA11 = Ab + (size_t)(brow * 256 + 192 + trow) * K2 + cc16;
    const uint8_t* pB00 = Bb + (size_t)(bcol * 256 +   0 + trow) * K2 + cc16;
    const uint8_t* pB01 = Bb + (size_t)(bcol * 256 +  64 + trow) * K2 + cc16;
    const uint8_t* pB10 = Bb + (size_t)(bcol * 256 + 128 + trow) * K2 + cc16;
    const uint8_t* pB11 = Bb + (size_t)(bcol * 256 + 192 + trow) * K2 + cc16;

    // ---- fragment read offsets (swizzled) ----
    const int lm = lane & 15, g = lane >> 4;
    const int sb0 = ((g ^ (lm & 7)) << 4);
    const int sb1 = (((g + 4) ^ (lm & 7)) << 4);
    const uint32_t aQ0 = (uint32_t)((wm * 128 +  0 + lm) * 128);
    const uint32_t aQ1 = (uint32_t)((wm * 128 + 64 + lm) * 128);
    const uint32_t bH0 = (uint32_t)(32768 + (wc * 64 +  0 + lm) * 128);
    const uint32_t bH1 = (uint32_t)(32768 + (wc * 64 + 32 + lm) * 128);

    f32x4 acc[8][4];
#pragma unroll
    for (int m = 0; m < 8; ++m)
#pragma unroll
        for (int n = 0; n < 4; ++n)
            acc[m][n] = (f32x4){0.f, 0.f, 0.f, 0.f};

    bf16x8 FA00, FA01, FA10, FA11, FA20, FA21, FA30, FA31;
    bf16x8 GA00, GA01, GA10, GA11, GA20, GA21, GA30, GA31;
    bf16x8 FB00, FB01, FB10, FB11;
    bf16x8 GB00, GB01, GB10, GB11;

    const int ntp = Ksl >> 7;    // K-tile pairs; launcher guarantees >= 2

    // Prologue: tile0 all 4 halves -> buf0; tile1 A0,A1,B0 -> buf1.
    STA(0, 0, 0); STA(1, 0, 0); STB(0, 0, 0); STB(1, 0, 0);
    STA(0, 128, 65536); STA(1, 128, 65536); STB(0, 128, 65536);
    VMC6;
    __builtin_amdgcn_s_barrier();
    __builtin_amdgcn_sched_barrier(0);

    for (int i = 0; i < ntp - 1; ++i) {
        const int kb = i * 256;
        // ---- K-tile 2i from buf0 ----
        RDA(FA, aQ0, 0); RDB(FB, bH0, 0);
        STB(1, kb + 128, 65536);
        PH_MID(); MFQ(FA, FB, 0, 0); PH_END();

        RDA(GA, aQ1, 0);
        PH_MID(); MFQ(GA, FB, 4, 0); PH_END();

        RDB(GB, bH1, 0);
        STA(0, kb + 256, 0); STA(1, kb + 256, 0);
        PH_MID(); MFQ(GA, GB, 4, 2); PH_END();

        STB(0, kb + 256, 0);
        VMC6;
        PH_MID(); MFQ(FA, GB, 0, 2); PH_END();

        // ---- K-tile 2i+1 from buf1 ----
        RDA(FA, aQ0, 65536); RDB(FB, bH0, 65536);
        STB(1, kb + 256, 0);
        PH_MID(); MFQ(FA, FB, 0, 0); PH_END();

        RDA(GA, aQ1, 65536);
        PH_MID(); MFQ(GA, FB, 4, 0); PH_END();

        RDB(GB, bH1, 65536);
        STA(0, kb + 384, 65536); STA(1, kb + 384, 65536);
        PH_MID(); MFQ(GA, GB, 4, 2); PH_END();

        STB(0, kb + 384, 65536);
        VMC6;
        PH_MID(); MFQ(FA, GB, 0, 2); PH_END();
    }
    {   // Tail pair.
        const int kb = (ntp - 1) * 256;
        RDA(FA, aQ0, 0); RDB(FB, bH0, 0);
        STB(1, kb + 128, 65536);
        PH_MID(); MFQ(FA, FB, 0, 0); PH_END();
        RDA(GA, aQ1, 0);
        PH_MID(); MFQ(GA, FB, 4, 0); PH_END();
        RDB(GB, bH1, 0);
        PH_MID(); MFQ(GA, GB, 4, 2); PH_END();
        VMC0;
        PH_MID(); MFQ(FA, GB, 0, 2); PH_END();

        RDA(FA, aQ0, 65536); RDB(FB, bH0, 65536);
        PH_MID(); MFQ(FA, FB, 0, 0); PH_END();
        RDA(GA, aQ1, 65536);
        PH_MID(); MFQ(GA, FB, 4, 0); PH_END();
        RDB(GB, bH1, 65536);
        PH_MID(); MFQ(GA, GB, 4, 2); PH_END();
        PH_MID(); MFQ(FA, GB, 0, 2); PH_END();
    }

    // Epilogue: plain stores to this slice's partial buffer.
    float* Pq = P + (size_t)slice * ((size_t)M * N);
    const int crow0 = brow * 256 + wm * 128 + (lane >> 4) * 4;
    const int ccol0 = bcol * 256 + wc * 64 + lm;
#pragma unroll
    for (int nf = 0; nf < 4; ++nf) {
        const int col = ccol0 + nf * 16;
        const float bv = (slice == 0) ? bias[col] : 0.f;
#pragma unroll
        for (int mf = 0; mf < 8; ++mf) {
#pragma unroll
            for (int tt = 0; tt < 4; ++tt) {
                const int row = crow0 + mf * 16 + tt;
                Pq[(size_t)row * N + col] = acc[mf][nf][tt] + bv;
            }
        }
    }
}

// ---------------------------------------------------------------------------
// Fallback 1: r4 phase-lagged kernel (75.3 us best): BM=128, BN=256, BK=64,
// ring-3 x 48 KiB, 8 waves, reg double-buffer.
// ---------------------------------------------------------------------------
#define GLDF(gp, lp) __builtin_amdgcn_global_load_lds(                          \
    (const __attribute__((address_space(1))) uint32_t*)(gp),                    \
    (__attribute__((address_space(3))) uint32_t*)(void*)(lp), 16, 0, 0)

#define STAGE6F(KOFF, BS) do {                                                  \
    GLDF(pA0 + (KOFF), (BS) + t16);                                             \
    GLDF(pA1 + (KOFF), (BS) + 8192  + t16);                                     \
    GLDF(pB0 + (KOFF), (BS) + 16384 + t16);                                     \
    GLDF(pB1 + (KOFF), (BS) + 24576 + t16);                                     \
    GLDF(pB2 + (KOFF), (BS) + 32768 + t16);                                     \
    GLDF(pB3 + (KOFF), (BS) + 40960 + t16);                                     \
} while (0)

#define READ8F(P, BASE, SX) do {                                                \
    P##a0 = *(const bf16x8*)((BASE) + (aoff0 ^ (SX)));                          \
    P##a1 = *(const bf16x8*)((BASE) + (aoff1 ^ (SX)));                          \
    P##a2 = *(const bf16x8*)((BASE) + (aoff2 ^ (SX)));                          \
    P##a3 = *(const bf16x8*)((BASE) + (aoff3 ^ (SX)));                          \
    P##b0 = *(const bf16x8*)((BASE) + (boff0 ^ (SX)));                          \
    P##b1 = *(const bf16x8*)((BASE) + (boff1 ^ (SX)));                          \
    P##b2 = *(const bf16x8*)((BASE) + (boff2 ^ (SX)));                          \
    P##b3 = *(const bf16x8*)((BASE) + (boff3 ^ (SX)));                          \
} while (0)

#define MFMA16F(P) do {                                                         \
    acc[0][0] = MM(P##a0, P##b0, acc[0][0]); acc[0][1] = MM(P##a0, P##b1, acc[0][1]); \
    acc[0][2] = MM(P##a0, P##b2, acc[0][2]); acc[0][3] = MM(P##a0, P##b3, acc[0][3]); \
    acc[1][0] = MM(P##a1, P##b0, acc[1][0]); acc[1][1] = MM(P##a1, P##b1, acc[1][1]); \
    acc[1][2] = MM(P##a1, P##b2, acc[1][2]); acc[1][3] = MM(P##a1, P##b3, acc[1][3]); \
    acc[2][0] = MM(P##a2, P##b0, acc[2][0]); acc[2][1] = MM(P##a2, P##b1, acc[2][1]); \
    acc[2][2] = MM(P##a2, P##b2, acc[2][2]); acc[2][3] = MM(P##a2, P##b3, acc[2][3]); \
    acc[3][0] = MM(P##a3, P##b0, acc[3][0]); acc[3][1] = MM(P##a3, P##b1, acc[3][1]); \
    acc[3][2] = MM(P##a3, P##b2, acc[3][2]); acc[3][3] = MM(P##a3, P##b3, acc[3][3]); \
} while (0)

#define ROT3F() do { uint8_t* t_ = r0; r0 = r1; r1 = r2; r2 = t_; } while (0)

#define PHASE_FULLF(R, M) do {                                                  \
    __builtin_amdgcn_s_barrier();                                               \
    __builtin_amdgcn_sched_barrier(0);                                          \
    READ8F(R##x, r0, 0);                                                        \
    __builtin_amdgcn_s_setprio(1); MFMA16F(M##x); __builtin_amdgcn_s_setprio(0);\
    STAGE6F(kk, r2);                                                            \
    READ8F(R##y, r0, 64);                                                       \
    __builtin_amdgcn_s_setprio(1); MFMA16F(M##y); __builtin_amdgcn_s_setprio(0);\
    asm volatile("s_waitcnt vmcnt(6)" ::: "memory");                            \
    ROT3F(); kk += 64;                                                          \
} while (0)

__global__ __launch_bounds__(512, 2) void gemm_pl_bf16(
    const uint16_t* __restrict__ A,
    const uint16_t* __restrict__ B,
    const float* __restrict__ bias,
    float* __restrict__ C, int M, int N, int K)
{
    extern __shared__ __align__(16) uint8_t lds[];
    const int tid  = threadIdx.x;
    const int lane = tid & 63;
    const int wave = tid >> 6;
    const int wr = wave >> 2;
    const int wc = wave & 3;

    const int nwg = gridDim.x;
    int swz;
    {
        const int q = nwg >> 3, r = nwg & 7;
        const int xcd = blockIdx.x & 7, k = blockIdx.x >> 3;
        swz = (xcd < r ? xcd * (q + 1) : r * (q + 1) + (xcd - r) * q) + k;
    }
    const int MB = M >> 7;
    const int brow = swz % MB;
    const int bcol = swz / MB;

    const int t16  = tid * 16;
    const int trow = tid >> 3;
    const int kc   = (tid & 7) ^ (trow & 7);
    const uint16_t* pA0 = A + (size_t)(brow * 128 + trow) * K + kc * 8;
    const uint16_t* pA1 = pA0 + (size_t)64 * K;
    const uint16_t* pB0 = B + (size_t)(bcol * 256 + trow) * K + kc * 8;
    const uint16_t* pB1 = pB0 + (size_t)64 * K;
    const uint16_t* pB2 = pB0 + (size_t)128 * K;
    const uint16_t* pB3 = pB0 + (size_t)192 * K;

    const int lm   = lane & 15;
    const int g    = lane >> 4;
    const int slot = (g ^ (lm & 7)) * 16;
    const int aoff0 = (wr * 64 +  0 + lm) * 128 + slot;
    const int aoff1 = (wr * 64 + 16 + lm) * 128 + slot;
    const int aoff2 = (wr * 64 + 32 + lm) * 128 + slot;
    const int aoff3 = (wr * 64 + 48 + lm) * 128 + slot;
    const int boff0 = 16384 + (wc * 64 +  0 + lm) * 128 + slot;
    const int boff1 = 16384 + (wc * 64 + 16 + lm) * 128 + slot;
    const int boff2 = 16384 + (wc * 64 + 32 + lm) * 128 + slot;
    const int boff3 = 16384 + (wc * 64 + 48 + lm) * 128 + slot;

    f32x4 acc[4][4];
#pragma unroll
    for (int m = 0; m < 4; ++m)
#pragma unroll
        for (int n = 0; n < 4; ++n)
            acc[m][n] = (f32x4){0.f, 0.f, 0.f, 0.f};

    bf16x8 exa0, exa1, exa2, exa3, exb0, exb1, exb2, exb3;
    bf16x8 eya0, eya1, eya2, eya3, eyb0, eyb1, eyb2, eyb3;
    bf16x8 oxa0, oxa1, oxa2, oxa3, oxb0, oxb1, oxb2, oxb3;
    bf16x8 oya0, oya1, oya2, oya3, oyb0, oyb1, oyb2, oyb3;

    const int nt = K >> 6;
    uint8_t* r0 = lds;
    uint8_t* r1 = lds + 49152;
    uint8_t* r2 = lds + 98304;
    size_t kk = 128;

    STAGE6F(0, r0);
    STAGE6F(64, r1);
    asm volatile("s_waitcnt vmcnt(6)" ::: "memory");

    __builtin_amdgcn_s_barrier();
    __builtin_amdgcn_sched_barrier(0);
    READ8F(ex, r0, 0);
    STAGE6F(kk, r2);
    READ8F(ey, r0, 64);
    asm volatile("s_waitcnt vmcnt(6)" ::: "memory");
    ROT3F(); kk += 64;

    for (int p = 1; p + 1 <= nt - 3; p += 2) {
        PHASE_FULLF(o, e);
        PHASE_FULLF(e, o);
    }
    PHASE_FULLF(o, e);

    __builtin_amdgcn_s_barrier();
    __builtin_amdgcn_sched_barrier(0);
    READ8F(ex, r0, 0);
    __builtin_amdgcn_s_setprio(1); MFMA16F(ox); __builtin_amdgcn_s_setprio(0);
    READ8F(ey, r0, 64);
    __builtin_amdgcn_s_setprio(1); MFMA16F(oy); __builtin_amdgcn_s_setprio(0);
    asm volatile("s_waitcnt vmcnt(0)" ::: "memory");
    ROT3F();

    __builtin_amdgcn_s_barrier();
    __builtin_amdgcn_sched_barrier(0);
    READ8F(ox, r0, 0);
    __builtin_amdgcn_s_setprio(1); MFMA16F(ex); __builtin_amdgcn_s_setprio(0);
    READ8F(oy, r0, 64);
    __builtin_amdgcn_s_setprio(1); MFMA16F(ey); __builtin_amdgcn_s_setprio(0);

    MFMA16F(ox);
    MFMA16F(oy);

    const int crow0 = brow * 128 + wr * 64 + (lane >> 4) * 4;
    const int ccol0 = bcol * 256 + wc * 64 + lm;
#pragma unroll
    for (int nf = 0; nf < 4; ++nf) {
        const int col = ccol0 + nf * 16;
        const float bv = bias[col];
#pragma unroll
        for (int mf = 0; mf < 4; ++mf) {
#pragma unroll
            for (int tt = 0; tt < 4; ++tt) {
                const int row = crow0 + mf * 16 + tt;
                C[(size_t)row * N + col] = acc[mf][nf][tt] + bv;
            }
        }
    }
}

// Fallback 2: fp32 vector GEMM, one block per row.
__global__ void gemm_fallback(const float* __restrict__ x, const float* __restrict__ w,
                              const float* __restrict__ bias, float* __restrict__ out,
                              int M, int N, int K) {
    extern __shared__ float xs[];
    const int b = blockIdx.x;
    for (int k = threadIdx.x; k < K; k += blockDim.x) xs[k] = x[(size_t)b * K + k];
    __syncthreads();
    for (int j = threadIdx.x; j < N; j += blockDim.x) {
        const float* wr = w + (size_t)j * K;
        float s = 0.f;
        for (int k = 0; k < K; ++k) s += xs[k] * wr[k];
        out[(size_t)b * N + j] = s + bias[j];
    }
}

extern "C" void kernel_launch(void* const* d_in, const int* in_sizes, int n_in,
                              void* d_out, int out_size, void* d_ws, size_t ws_size,
                              hipStream_t stream) {
    const float* x    = (const float*)d_in[0];
    const float* w    = (const float*)d_in[1];
    const float* bias = (const float*)d_in[2];
    float* out = (float*)d_out;

    const int N = in_sizes[2];
    const int K = in_sizes[1] / N;
    const int M = in_sizes[0] / K;

    const size_t bf16_need = ((size_t)M * K + (size_t)N * K) * 2;
    const size_t part_need = (size_t)2 * (size_t)M * N * 4;

    if ((M % 256 == 0) && (N % 256 == 0) && (K % 256 == 0) && (K >= 512) &&
        ws_size >= bf16_need + part_need) {
        uint16_t* xb = (uint16_t*)d_ws;
        uint16_t* wb = xb + (size_t)M * K;
        float* P = (float*)(wb + (size_t)N * K);       // 16B-aligned for MK+NK even
        const long na4 = (long)M * K / 4, nb4 = (long)N * K / 4;
        cvt2_kernel<<<2048, 256, 0, stream>>>(x, na4, w, nb4, xb, wb);
        (void)hipFuncSetAttribute((const void*)gemm_sk_bf16,
                                  hipFuncAttributeMaxDynamicSharedMemorySize, 131072);
        dim3 grid(2 * (M / 256) * (N / 256));
        gemm_sk_bf16<<<grid, 512, 131072, stream>>>(xb, wb, bias, P, M, N, K);
        const long n4 = (long)M * N / 4;
        reduce2_kernel<<<2048, 256, 0, stream>>>((const float4*)P,
                                                 (const float4*)(P + (size_t)M * N),
                                                 (float4*)out, n4);
    } else if ((M % 128 == 0) && (N % 256 == 0) && (K % 128 == 0) && (K >= 256) &&
               ws_size >= bf16_need) {
        uint16_t* xb = (uint16_t*)d_ws;
        uint16_t* wb = xb + (size_t)M * K;
        const long na4 = (long)M * K / 4, nb4 = (long)N * K / 4;
        cvt2_kernel<<<2048, 256, 0, stream>>>(x, na4, w, nb4, xb, wb);
        (void)hipFuncSetAttribute((const void*)gemm_pl_bf16,
                                  hipFuncAttributeMaxDynamicSharedMemorySize, 147456);
        dim3 grid((M / 128) * (N / 256));
        gemm_pl_bf16<<<grid, 512, 147456, stream>>>(xb, wb, bias, out, M, N, K);
    } else {
        gemm_fallback<<<M, 256, (size_t)K * 4, stream>>>(x, w, bias, out, M, N, K);
    }
}

// Round 10
// 86.708 us; speedup vs baseline: 1.8413x; 1.5473x over previous
//
#include <hip/hip_runtime.h>
#include <hip/hip_bf16.h>
#include <stdint.h>

typedef __bf16 bf16x8 __attribute__((ext_vector_type(8)));
typedef float f32x4 __attribute__((ext_vector_type(4)));

__device__ __forceinline__ uint16_t f32_to_bf16_rne(float f) {
    uint32_t u = __float_as_uint(f);
    u += 0x7fffu + ((u >> 16) & 1u);
    return (uint16_t)(u >> 16);
}

// Convert two fp32 arrays to bf16 (RNE) in one grid-stride kernel.
__global__ void cvt2_kernel(const float* __restrict__ a, long na4,
                            const float* __restrict__ b, long nb4,
                            uint16_t* __restrict__ oa, uint16_t* __restrict__ ob) {
    long i = (long)blockIdx.x * blockDim.x + threadIdx.x;
    const long stride = (long)gridDim.x * blockDim.x;
    const long tot = na4 + nb4;
    for (; i < tot; i += stride) {
        const float4* src; ushort4* dst; long j;
        if (i < na4) { src = (const float4*)a; dst = (ushort4*)oa; j = i; }
        else         { src = (const float4*)b; dst = (ushort4*)ob; j = i - na4; }
        float4 f = src[j];
        ushort4 o;
        o.x = f32_to_bf16_rne(f.x);
        o.y = f32_to_bf16_rne(f.y);
        o.z = f32_to_bf16_rne(f.z);
        o.w = f32_to_bf16_rne(f.w);
        dst[j] = o;
    }
}

// ---------------------------------------------------------------------------
// r4-verified phase-lagged GEMM (75.3 us GEMM / 87.0 us total), with two
// evidence-backed deltas: no setprio (m190: negative on lockstep GEMM) and
// no sched_barrier(0) (m141: order-pinning costs; reads may legally hoist
// above s_barrier — they only depend on the previous phase's vmcnt, which
// the asm "memory" clobber still orders).
// BM=128, BN=256, BK=64/phase, 8 waves (2M x 4N), wave 64x64 output.
// Ring of 3 LDS regions x 48 KiB = 144 KiB:
//   region: A[128r][64k] bf16 (16 KiB) + B[256r][64k] (32 KiB at +16384).
// Rows 128 B; 16-B chunk c of row r at slot c ^ (r&7) (measured 0-conflict).
// Phase p: barrier; read region p -> set S(p); MFMA set S(p-1); stage
// region p+2; vmcnt(6) (publishes region p+1 pre-barrier -> race-free).
// MFMA never depends on same-phase ds_reads (full-phase register slack).
// ---------------------------------------------------------------------------

#define GLD(gp, lp) __builtin_amdgcn_global_load_lds(                           \
    (const __attribute__((address_space(1))) uint32_t*)(gp),                    \
    (__attribute__((address_space(3))) uint32_t*)(void*)(lp), 16, 0, 0)

#define MM(a, b, c) __builtin_amdgcn_mfma_f32_16x16x32_bf16(a, b, c, 0, 0, 0)

// Stage one K64 region (A: 2 issues, B: 4 issues; 6 vmcnt items/wave).
#define STAGE6(KOFF, BS) do {                                                   \
    GLD(pA0 + (KOFF), (BS) + t16);                                              \
    GLD(pA1 + (KOFF), (BS) + 8192  + t16);                                      \
    GLD(pB0 + (KOFF), (BS) + 16384 + t16);                                      \
    GLD(pB1 + (KOFF), (BS) + 24576 + t16);                                      \
    GLD(pB2 + (KOFF), (BS) + 32768 + t16);                                      \
    GLD(pB3 + (KOFF), (BS) + 40960 + t16);                                      \
} while (0)

// Read 4 A-frags + 4 B-frags (one K32 half; SX=0 -> k[0,32), SX=64 -> k[32,64)).
#define READ8(P, BASE, SX) do {                                                 \
    P##a0 = *(const bf16x8*)((BASE) + (aoff0 ^ (SX)));                          \
    P##a1 = *(const bf16x8*)((BASE) + (aoff1 ^ (SX)));                          \
    P##a2 = *(const bf16x8*)((BASE) + (aoff2 ^ (SX)));                          \
    P##a3 = *(const bf16x8*)((BASE) + (aoff3 ^ (SX)));                          \
    P##b0 = *(const bf16x8*)((BASE) + (boff0 ^ (SX)));                          \
    P##b1 = *(const bf16x8*)((BASE) + (boff1 ^ (SX)));                          \
    P##b2 = *(const bf16x8*)((BASE) + (boff2 ^ (SX)));                          \
    P##b3 = *(const bf16x8*)((BASE) + (boff3 ^ (SX)));                          \
} while (0)

#define MFMA16(P) do {                                                          \
    acc[0][0] = MM(P##a0, P##b0, acc[0][0]); acc[0][1] = MM(P##a0, P##b1, acc[0][1]); \
    acc[0][2] = MM(P##a0, P##b2, acc[0][2]); acc[0][3] = MM(P##a0, P##b3, acc[0][3]); \
    acc[1][0] = MM(P##a1, P##b0, acc[1][0]); acc[1][1] = MM(P##a1, P##b1, acc[1][1]); \
    acc[1][2] = MM(P##a1, P##b2, acc[1][2]); acc[1][3] = MM(P##a1, P##b3, acc[1][3]); \
    acc[2][0] = MM(P##a2, P##b0, acc[2][0]); acc[2][1] = MM(P##a2, P##b1, acc[2][1]); \
    acc[2][2] = MM(P##a2, P##b2, acc[2][2]); acc[2][3] = MM(P##a2, P##b3, acc[2][3]); \
    acc[3][0] = MM(P##a3, P##b0, acc[3][0]); acc[3][1] = MM(P##a3, P##b1, acc[3][1]); \
    acc[3][2] = MM(P##a3, P##b2, acc[3][2]); acc[3][3] = MM(P##a3, P##b3, acc[3][3]); \
} while (0)

#define ROT3() do { uint8_t* t_ = r0; r0 = r1; r1 = r2; r2 = t_; } while (0)

// Full phase: read set R from region r0, MFMA set M (read last phase),
// stage into r2, counted vmcnt at end (publishes region p+1).
#define PHASE_FULL(R, M) do {                                                   \
    __builtin_amdgcn_s_barrier();                                               \
    READ8(R##x, r0, 0);                                                         \
    MFMA16(M##x);                                                               \
    STAGE6(kk, r2);                                                             \
    READ8(R##y, r0, 64);                                                        \
    MFMA16(M##y);                                                               \
    asm volatile("s_waitcnt vmcnt(6)" ::: "memory");                            \
    ROT3(); kk += 64;                                                           \
} while (0)

__global__ __launch_bounds__(512, 2) void gemm_pl_bf16(
    const uint16_t* __restrict__ A,   // M x K bf16 (x)
    const uint16_t* __restrict__ B,   // N x K bf16 (weight)
    const float* __restrict__ bias,
    float* __restrict__ C, int M, int N, int K)
{
    extern __shared__ __align__(16) uint8_t lds[];
    const int tid  = threadIdx.x;
    const int lane = tid & 63;
    const int wave = tid >> 6;
    const int wr = wave >> 2;   // 0..1 (M)
    const int wc = wave & 3;    // 0..3 (N)

    // Bijective XCD-aware swizzle.
    const int nwg = gridDim.x;
    int swz;
    {
        const int q = nwg >> 3, r = nwg & 7;
        const int xcd = blockIdx.x & 7, k = blockIdx.x >> 3;
        swz = (xcd < r ? xcd * (q + 1) : r * (q + 1) + (xcd - r) * q) + k;
    }
    const int MB = M >> 7;
    const int brow = swz % MB;
    const int bcol = swz / MB;

    // Staging addressing (pre-swizzled global source, linear LDS dest).
    const int t16  = tid * 16;
    const int trow = tid >> 3;                       // 0..63
    const int kc   = (tid & 7) ^ (trow & 7);         // swizzled 16B-chunk index
    const uint16_t* pA0 = A + (size_t)(brow * 128 + trow) * K + kc * 8;
    const uint16_t* pA1 = pA0 + (size_t)64 * K;
    const uint16_t* pB0 = B + (size_t)(bcol * 256 + trow) * K + kc * 8;
    const uint16_t* pB1 = pB0 + (size_t)64 * K;
    const uint16_t* pB2 = pB0 + (size_t)128 * K;
    const uint16_t* pB3 = pB0 + (size_t)192 * K;

    // Fragment read offsets (region-relative), swizzled.
    const int lm   = lane & 15;
    const int g    = lane >> 4;
    const int slot = (g ^ (lm & 7)) * 16;
    const int aoff0 = (wr * 64 +  0 + lm) * 128 + slot;
    const int aoff1 = (wr * 64 + 16 + lm) * 128 + slot;
    const int aoff2 = (wr * 64 + 32 + lm) * 128 + slot;
    const int aoff3 = (wr * 64 + 48 + lm) * 128 + slot;
    const int boff0 = 16384 + (wc * 64 +  0 + lm) * 128 + slot;
    const int boff1 = 16384 + (wc * 64 + 16 + lm) * 128 + slot;
    const int boff2 = 16384 + (wc * 64 + 32 + lm) * 128 + slot;
    const int boff3 = 16384 + (wc * 64 + 48 + lm) * 128 + slot;

    f32x4 acc[4][4];
#pragma unroll
    for (int m = 0; m < 4; ++m)
#pragma unroll
        for (int n = 0; n < 4; ++n)
            acc[m][n] = (f32x4){0.f, 0.f, 0.f, 0.f};

    // Register fragment sets (E/O alternate by phase parity; x/y = K32 halves).
    bf16x8 exa0, exa1, exa2, exa3, exb0, exb1, exb2, exb3;
    bf16x8 eya0, eya1, eya2, eya3, eyb0, eyb1, eyb2, eyb3;
    bf16x8 oxa0, oxa1, oxa2, oxa3, oxb0, oxb1, oxb2, oxb3;
    bf16x8 oya0, oya1, oya2, oya3, oyb0, oyb1, oyb2, oyb3;

    const int nt = K >> 6;   // K64 phases; launcher guarantees even, >= 4
    uint8_t* r0 = lds;
    uint8_t* r1 = lds + 49152;
    uint8_t* r2 = lds + 98304;
    size_t kk = 128;         // k-element offset staged by the current phase

    // Prologue: stage regions 0,1; cover region 0.
    STAGE6(0, r0);
    STAGE6(64, r1);
    asm volatile("s_waitcnt vmcnt(6)" ::: "memory");

    // Phase 0 (reads E, no MFMA, stages region 2).
    __builtin_amdgcn_s_barrier();
    READ8(ex, r0, 0);
    STAGE6(kk, r2);
    READ8(ey, r0, 64);
    asm volatile("s_waitcnt vmcnt(6)" ::: "memory");
    ROT3(); kk += 64;

    // Pairs: phases 1..nt-4 (odd reads O / even reads E).
    for (int p = 1; p + 1 <= nt - 3; p += 2) {
        PHASE_FULL(o, e);
        PHASE_FULL(e, o);
    }
    // Phase nt-3 (odd): full.
    PHASE_FULL(o, e);

    // Phase nt-2 (even): no stage; drain remaining (region nt-1) pre-barrier.
    __builtin_amdgcn_s_barrier();
    READ8(ex, r0, 0);
    MFMA16(ox);
    READ8(ey, r0, 64);
    MFMA16(oy);
    asm volatile("s_waitcnt vmcnt(0)" ::: "memory");
    ROT3();

    // Phase nt-1 (odd): last reads.
    __builtin_amdgcn_s_barrier();
    READ8(ox, r0, 0);
    MFMA16(ex);
    READ8(oy, r0, 64);
    MFMA16(ey);

    // Final: consume the last-read set.
    MFMA16(ox);
    MFMA16(oy);

    // Epilogue: D mapping col = lane&15 (N), row = (lane>>4)*4 + t (M).
    const int crow0 = brow * 128 + wr * 64 + (lane >> 4) * 4;
    const int ccol0 = bcol * 256 + wc * 64 + lm;
#pragma unroll
    for (int nf = 0; nf < 4; ++nf) {
        const int col = ccol0 + nf * 16;
        const float bv = bias[col];
#pragma unroll
        for (int mf = 0; mf < 4; ++mf) {
#pragma unroll
            for (int tt = 0; tt < 4; ++tt) {
                const int row = crow0 + mf * 16 + tt;
                C[(size_t)row * N + col] = acc[mf][nf][tt] + bv;
            }
        }
    }
}

// ---------------------------------------------------------------------------
// Fallback 1: verified m97-structure 128x128 kernel.
// ---------------------------------------------------------------------------
__global__ __launch_bounds__(256) void gemm_bf16_kernel(
    const uint16_t* __restrict__ A,
    const uint16_t* __restrict__ B,
    const float* __restrict__ bias,
    float* __restrict__ C, int M, int N, int K)
{
    __shared__ __align__(16) uint16_t Alds[128 * 32];
    __shared__ __align__(16) uint16_t Blds[128 * 32];

    const int tid  = threadIdx.x;
    const int lane = tid & 63;
    const int wave = tid >> 6;
    const int wm = wave >> 1, wn = wave & 1;

    const int MBl = M >> 7;
    const int brow = blockIdx.x % MBl;
    const int bcol = blockIdx.x / MBl;

    const int off0 = wave * 1024 + lane * 16;
    const int row0 = off0 >> 6;
    const int colb = off0 & 63;

    const uint8_t* gA0 = (const uint8_t*)A + ((size_t)(brow * 128 + row0) * K) * 2 + colb;
    const uint8_t* gA1 = gA0 + (size_t)64 * K * 2;
    const uint8_t* gB0 = (const uint8_t*)B + ((size_t)(bcol * 128 + row0) * K) * 2 + colb;
    const uint8_t* gB1 = gB0 + (size_t)64 * K * 2;

    uint32_t* lA0 = (uint32_t*)((uint8_t*)Alds + off0);
    uint32_t* lA1 = (uint32_t*)((uint8_t*)Alds + off0 + 4096);
    uint32_t* lB0 = (uint32_t*)((uint8_t*)Blds + off0);
    uint32_t* lB1 = (uint32_t*)((uint8_t*)Blds + off0 + 4096);

#define STAGE_OLD() do {                                                                   \
    __builtin_amdgcn_global_load_lds((const __attribute__((address_space(1))) uint32_t*)gA0, \
                                     (__attribute__((address_space(3))) uint32_t*)lA0, 16, 0, 0); \
    __builtin_amdgcn_global_load_lds((const __attribute__((address_space(1))) uint32_t*)gA1, \
                                     (__attribute__((address_space(3))) uint32_t*)lA1, 16, 0, 0); \
    __builtin_amdgcn_global_load_lds((const __attribute__((address_space(1))) uint32_t*)gB0, \
                                     (__attribute__((address_space(3))) uint32_t*)lB0, 16, 0, 0); \
    __builtin_amdgcn_global_load_lds((const __attribute__((address_space(1))) uint32_t*)gB1, \
                                     (__attribute__((address_space(3))) uint32_t*)lB1, 16, 0, 0); \
    gA0 += 64; gA1 += 64; gB0 += 64; gB1 += 64;                                            \
} while (0)

    f32x4 acc[4][4];
#pragma unroll
    for (int mf = 0; mf < 4; ++mf)
#pragma unroll
        for (int nf = 0; nf < 4; ++nf)
            acc[mf][nf] = (f32x4){0.f, 0.f, 0.f, 0.f};

    const int nk = K >> 5;
    STAGE_OLD();

    const int arow = wm * 64 + (lane & 15);
    const int brw  = wn * 64 + (lane & 15);
    const int ke   = (lane >> 4) * 8;

    for (int kt = 0; kt < nk; ++kt) {
        __syncthreads();
        bf16x8 af[4], bfr[4];
#pragma unroll
        for (int mf = 0; mf < 4; ++mf)
            af[mf] = *(const bf16x8*)(&Alds[(arow + mf * 16) * 32 + ke]);
#pragma unroll
        for (int nf = 0; nf < 4; ++nf)
            bfr[nf] = *(const bf16x8*)(&Blds[(brw + nf * 16) * 32 + ke]);
        __syncthreads();
        if (kt + 1 < nk) STAGE_OLD();
#pragma unroll
        for (int mf = 0; mf < 4; ++mf)
#pragma unroll
            for (int nf = 0; nf < 4; ++nf)
                acc[mf][nf] = __builtin_amdgcn_mfma_f32_16x16x32_bf16(
                    af[mf], bfr[nf], acc[mf][nf], 0, 0, 0);
    }
#undef STAGE_OLD

    const int crow0 = brow * 128 + wm * 64 + (lane >> 4) * 4;
    const int ccol0 = bcol * 128 + wn * 64 + (lane & 15);
#pragma unroll
    for (int nf = 0; nf < 4; ++nf) {
        const int col = ccol0 + nf * 16;
        const float bv = bias[col];
#pragma unroll
        for (int mf = 0; mf < 4; ++mf) {
#pragma unroll
            for (int t = 0; t < 4; ++t) {
                const int row = crow0 + mf * 16 + t;
                C[(size_t)row * N + col] = acc[mf][nf][t] + bv;
            }
        }
    }
}

// Fallback 2: fp32 vector GEMM, one block per row.
__global__ void gemm_fallback(const float* __restrict__ x, const float* __restrict__ w,
                              const float* __restrict__ bias, float* __restrict__ out,
                              int M, int N, int K) {
    extern __shared__ float xs[];
    const int b = blockIdx.x;
    for (int k = threadIdx.x; k < K; k += blockDim.x) xs[k] = x[(size_t)b * K + k];
    __syncthreads();
    for (int j = threadIdx.x; j < N; j += blockDim.x) {
        const float* wr = w + (size_t)j * K;
        float s = 0.f;
        for (int k = 0; k < K; ++k) s += xs[k] * wr[k];
        out[(size_t)b * N + j] = s + bias[j];
    }
}

extern "C" void kernel_launch(void* const* d_in, const int* in_sizes, int n_in,
                              void* d_out, int out_size, void* d_ws, size_t ws_size,
                              hipStream_t stream) {
    const float* x    = (const float*)d_in[0];
    const float* w    = (const float*)d_in[1];
    const float* bias = (const float*)d_in[2];
    float* out = (float*)d_out;

    const int N = in_sizes[2];
    const int K = in_sizes[1] / N;
    const int M = in_sizes[0] / K;

    const size_t need = ((size_t)M * K + (size_t)N * K) * 2;
    const bool ws_ok = ws_size >= need;

    if ((M % 128 == 0) && (N % 256 == 0) && (K % 128 == 0) && (K >= 256) && ws_ok) {
        uint16_t* xb = (uint16_t*)d_ws;
        uint16_t* wb = xb + (size_t)M * K;
        const long na4 = (long)M * K / 4, nb4 = (long)N * K / 4;
        cvt2_kernel<<<2048, 256, 0, stream>>>(x, na4, w, nb4, xb, wb);
        (void)hipFuncSetAttribute((const void*)gemm_pl_bf16,
                                  hipFuncAttributeMaxDynamicSharedMemorySize, 147456);
        dim3 grid((M / 128) * (N / 256));
        gemm_pl_bf16<<<grid, 512, 147456, stream>>>(xb, wb, bias, out, M, N, K);
    } else if ((M % 128 == 0) && (N % 128 == 0) && (K % 32 == 0) && ws_ok) {
        uint16_t* xb = (uint16_t*)d_ws;
        uint16_t* wb = xb + (size_t)M * K;
        const long na4 = (long)M * K / 4, nb4 = (long)N * K / 4;
        cvt2_kernel<<<2048, 256, 0, stream>>>(x, na4, w, nb4, xb, wb);
        dim3 grid((M / 128) * (N / 128));
        gemm_bf16_kernel<<<grid, 256, 0, stream>>>(xb, wb, bias, out, M, N, K);
    } else {
        gemm_fallback<<<M, 256, (size_t)K * 4, stream>>>(x, w, bias, out, M, N, K);
    }
}